// Round 15
// baseline (15446.410 us; speedup 1.0000x reference)
//
#include <hip/hip_runtime.h>
#include <hip/hip_fp16.h>

#define Bn 256
#define Sn 128
#define Hn 512
#define G4 2048
#define NBLK 256
#define NTHR 1024
#define HSTR 516   // padded LDS stride (floats)
#define LOG2E 1.4426950408889634f

typedef float f4v __attribute__((ext_vector_type(4)));

// ---- LSTM gates: ocml-based (bit-identical recurrence to rounds 10/12/13/14) ----
__device__ __forceinline__ float sigf(float x){
    float e = expf(-fabsf(x));
    float d = 1.f + e;
    return x >= 0.f ? 1.f/d : e/d;
}
// ---- attention-only fast tanh (validated r12/r13/r14: absmax 0.03125) ----
__device__ __forceinline__ float ftanh(float x){
    float e = __builtin_amdgcn_exp2f(-2.f * LOG2E * fabsf(x));
    float t = (1.f - e) * __builtin_amdgcn_rcpf(1.f + e);
    return copysignf(t, x);
}

// Agent-scope coherent access (coherence point, no L2 inv/wb).
__device__ __forceinline__ float cload(const float* p){
    return __hip_atomic_load((float*)p, __ATOMIC_RELAXED, __HIP_MEMORY_SCOPE_AGENT);
}
__device__ __forceinline__ void cstore(float* p, float v){
    __hip_atomic_store(p, v, __ATOMIC_RELAXED, __HIP_MEMORY_SCOPE_AGENT);
}
// Wide coherence-point load: volatile lowers to global_load_dwordx4 sc0 sc1
// (empirically coherent across XCDs: rounds 10/12/13/14 h-exchange correctness).
__device__ __forceinline__ f4v vload4(const float* p){
    return *(volatile const f4v*)p;
}

// ---- slot-store group barrier (16 blocks): no atomic RMW on the hot path ----
__device__ __forceinline__ void gbar(unsigned* slots, unsigned k, int grp){
    __syncthreads();
    if (threadIdx.x < 64) {
        if (threadIdx.x == 0)
            __hip_atomic_store(slots + grp, k, __ATOMIC_RELAXED, __HIP_MEMORY_SCOPE_AGENT);
        unsigned v = (threadIdx.x < 16)
            ? __hip_atomic_load(slots + threadIdx.x, __ATOMIC_RELAXED, __HIP_MEMORY_SCOPE_AGENT)
            : k;
        while (__ballot(v < k)) {
            __builtin_amdgcn_s_sleep(1);
            v = (threadIdx.x < 16)
                ? __hip_atomic_load(slots + threadIdx.x, __ATOMIC_RELAXED, __HIP_MEMORY_SCOPE_AGENT)
                : k;
        }
        asm volatile("" ::: "memory");
    }
    __syncthreads();
}
// One-shot transition barrier: release (wbl2) + acquire (inv) for w1enc handoff.
__device__ __forceinline__ void gbar_sys(unsigned* cnt){
    __syncthreads();
    if (threadIdx.x == 0) {
        __hip_atomic_fetch_add(cnt, 1u, __ATOMIC_RELEASE, __HIP_MEMORY_SCOPE_AGENT);
        while (__hip_atomic_load(cnt, __ATOMIC_RELAXED, __HIP_MEMORY_SCOPE_AGENT) < 16u)
            __builtin_amdgcn_s_sleep(1);
        (void)__hip_atomic_load(cnt, __ATOMIC_ACQUIRE, __HIP_MEMORY_SCOPE_AGENT);
    }
    __syncthreads();
}

// ---- rank-1 collapse of the input-side GEMMs (F_IN == 1) ----
__global__ void precompute_kernel(
    const float* __restrict__ Wih_e, const float* __restrict__ We_e,
    const float* __restrict__ be_e,  const float* __restrict__ b_e,
    const float* __restrict__ Wih_d, const float* __restrict__ We_d,
    const float* __restrict__ be_d,  const float* __restrict__ b_d,
    float* __restrict__ p1, float* __restrict__ p0,
    float* __restrict__ r1, float* __restrict__ r0)
{
    int j = blockIdx.x*blockDim.x + threadIdx.x;   // 0..4095
    bool dec = j >= G4;
    int jj = dec ? j - G4 : j;
    const float* Wih = dec ? Wih_d : Wih_e;
    const float* We  = dec ? We_d  : We_e;
    const float* be  = dec ? be_d  : be_e;
    const float* bb  = dec ? b_d   : b_e;
    float s1 = 0.f, s0 = 0.f;
    for (int k = 0; k < Hn; ++k) {
        float w = Wih[jj*Hn + k];
        s1 += w * We[k];
        s0 += w * be[k];
    }
    s0 += bb[jj];
    if (dec) { r1[jj] = s1; r0[jj] = s0; }
    else     { p1[jj] = s1; p0[jj] = s0; }
}

// ---- whole pointer network, one persistent kernel ----
// Decoder reduced to 2 phases/step: (LSTM) -> (fused q + attention).
// q computed redundantly per attn block (block = batch): W2 is L2/L3-shared.
__global__ __launch_bounds__(NTHR, 4) void ptrnet_kernel(
    const float* __restrict__ xseq,
    const float* __restrict__ Whh_e, const float* __restrict__ Whh_d,
    const float* __restrict__ W1, const float* __restrict__ b1,
    const float* __restrict__ W2, const float* __restrict__ b2,
    const float* __restrict__ vv,
    const float* __restrict__ p1, const float* __restrict__ p0,
    const float* __restrict__ r1, const float* __restrict__ r0,
    float* __restrict__ hb0, float* __restrict__ hb1,
    float* __restrict__ cbuf,
    float* __restrict__ x_in, float* __restrict__ w1enc,
    unsigned* __restrict__ barb,
    float* __restrict__ out_scores, float* __restrict__ out_ptr)
{
    __shared__ float smem[16*HSTR + 512*5 + 16];   // 43.3 KB
    float* hs  = smem;                 // [16][HSTR] h-tile (LSTM phases)
    float* red = smem + 16*HSTR;       // split-k partials
    // attn-phase aliases (phases disjoint):
    float* hds = smem;                 // 512 staged hd[b]
    float* qsf = smem + Hn;            // 512 q values
    float* us  = smem + 2*Hn;          // 128 logits
    float* rr  = smem + 2*Hn + Sn + 8; // {max, log-sum-exp}

    const int blk = blockIdx.x;
    const int tid = threadIdx.x;
    const int bt  = blk >> 4, grp = blk & 15;
    const int b0  = bt << 4;
    const int tb  = tid & 15;
    const int hh  = (tid >> 4) & 31;
    const int ks  = tid >> 9;
    const int hg  = (grp << 5) + hh;
    const int kofs = ks << 8;
    unsigned* slots  = barb + bt*64;           // 16 slots in one 64B line
    unsigned* syscnt = barb + 1024 + bt*64;    // one-shot transition counter
    unsigned bk = 0;
    float* hprev = hb0;
    float* hnext = hb1;

    // v is loop-invariant: hoist per-lane slice into registers
    const int l64 = tid & 63;
    const int kb = l64 << 3;
    float vreg[8];
    #pragma unroll
    for (int j = 0; j < 8; ++j) vreg[j] = vv[kb+j];

// 16 rows x 512 floats = 2048 f4v over 1024 threads: 2 coherent 16B loads each.
#define STAGE_H(SRC) do { \
    for (int i_ = tid; i_ < 16*128; i_ += NTHR) { \
        int r_ = i_ >> 7; int c4_ = (i_ & 127) << 2; \
        *(f4v*)(hs + r_*HSTR + c4_) = vload4((SRC) + (size_t)(b0+r_)*Hn + c4_); \
    } __syncthreads(); } while(0)

    // ================= encoder: t = 0..128 (t==128 emits only w1enc[127]) ===
    for (int t = 0; t <= Sn; ++t) {
        STAGE_H(hprev);
        float a0=0.f,a1=0.f,a2=0.f,a3=0.f,a4=0.f;
        {
            const float* hrow = hs + tb*HSTR + kofs;
            const float* w0 = Whh_e + (size_t)hg*Hn          + kofs;
            const float* w1r= Whh_e + (size_t)(Hn+hg)*Hn     + kofs;
            const float* w2r= Whh_e + (size_t)(2*Hn+hg)*Hn   + kofs;
            const float* w3r= Whh_e + (size_t)(3*Hn+hg)*Hn   + kofs;
            const float* w4r= W1    + (size_t)hg*Hn          + kofs;
            for (int i = 0; i < 256; i += 4) {
                float4 hv = *(const float4*)(hrow + i);
                float4 x0 = *(const float4*)(w0 + i);
                float4 x1 = *(const float4*)(w1r + i);
                float4 x2 = *(const float4*)(w2r + i);
                float4 x3 = *(const float4*)(w3r + i);
                float4 x4 = *(const float4*)(w4r + i);
                a0 += hv.x*x0.x + hv.y*x0.y + hv.z*x0.z + hv.w*x0.w;
                a1 += hv.x*x1.x + hv.y*x1.y + hv.z*x1.z + hv.w*x1.w;
                a2 += hv.x*x2.x + hv.y*x2.y + hv.z*x2.z + hv.w*x2.w;
                a3 += hv.x*x3.x + hv.y*x3.y + hv.z*x3.z + hv.w*x3.w;
                a4 += hv.x*x4.x + hv.y*x4.y + hv.z*x4.z + hv.w*x4.w;
            }
        }
        if (ks) {
            float* rp = red + (size_t)(tid - 512)*5;
            rp[0]=a0; rp[1]=a1; rp[2]=a2; rp[3]=a3; rp[4]=a4;
        }
        __syncthreads();
        if (!ks) {
            const float* rp = red + (size_t)tid*5;
            a0+=rp[0]; a1+=rp[1]; a2+=rp[2]; a3+=rp[3]; a4+=rp[4];
            size_t off = (size_t)(b0+tb)*Hn + hg;
            if (t < Sn) {
                float xv = xseq[(b0+tb)*Sn + t];
                float gi = a0 + xv*p1[hg]      + p0[hg];
                float gf = a1 + xv*p1[Hn+hg]   + p0[Hn+hg];
                float gg = a2 + xv*p1[2*Hn+hg] + p0[2*Hn+hg];
                float go = a3 + xv*p1[3*Hn+hg] + p0[3*Hn+hg];
                float cn = sigf(gf)*cbuf[off] + sigf(gi)*tanhf(gg);
                float hn = sigf(go)*tanhf(cn);
                cbuf[off] = cn;
                cstore(hnext + off, hn);
            }
            if (t > 0)
                w1enc[((size_t)(b0+tb)*Sn + (t-1))*Hn + hg] = a4 + b1[hg];
        }
        if (t == Sn) gbar_sys(syscnt);     // w1enc handoff: wbl2 + inv (once)
        else         { ++bk; gbar(slots, bk, grp); }
        if (t < Sn) { float* tp = hprev; hprev = hnext; hnext = tp; }
    }

    // ============ decoder: 128 steps of LSTM -> (fused q + attention) =======
    for (int t = 0; t < Sn; ++t) {
        // ---- dec LSTM ----
        STAGE_H(hprev);
        float a0=0.f,a1=0.f,a2=0.f,a3=0.f;
        {
            const float* hrow = hs + tb*HSTR + kofs;
            const float* w0 = Whh_d + (size_t)hg*Hn        + kofs;
            const float* w1r= Whh_d + (size_t)(Hn+hg)*Hn   + kofs;
            const float* w2r= Whh_d + (size_t)(2*Hn+hg)*Hn + kofs;
            const float* w3r= Whh_d + (size_t)(3*Hn+hg)*Hn + kofs;
            for (int i = 0; i < 256; i += 4) {
                float4 hv = *(const float4*)(hrow + i);
                float4 x0 = *(const float4*)(w0 + i);
                float4 x1 = *(const float4*)(w1r + i);
                float4 x2 = *(const float4*)(w2r + i);
                float4 x3 = *(const float4*)(w3r + i);
                a0 += hv.x*x0.x + hv.y*x0.y + hv.z*x0.z + hv.w*x0.w;
                a1 += hv.x*x1.x + hv.y*x1.y + hv.z*x1.z + hv.w*x1.w;
                a2 += hv.x*x2.x + hv.y*x2.y + hv.z*x2.z + hv.w*x2.w;
                a3 += hv.x*x3.x + hv.y*x3.y + hv.z*x3.z + hv.w*x3.w;
            }
        }
        if (ks) {
            float* rp = red + (size_t)(tid - 512)*4;
            rp[0]=a0; rp[1]=a1; rp[2]=a2; rp[3]=a3;
        }
        __syncthreads();
        if (!ks) {
            const float* rp = red + (size_t)tid*4;
            a0+=rp[0]; a1+=rp[1]; a2+=rp[2]; a3+=rp[3];
            size_t off = (size_t)(b0+tb)*Hn + hg;
            float xv = cload(x_in + b0 + tb);
            float gi = a0 + xv*r1[hg]      + r0[hg];
            float gf = a1 + xv*r1[Hn+hg]   + r0[Hn+hg];
            float gg = a2 + xv*r1[2*Hn+hg] + r0[2*Hn+hg];
            float go = a3 + xv*r1[3*Hn+hg] + r0[3*Hn+hg];
            float cn = sigf(gf)*cbuf[off] + sigf(gi)*tanhf(gg);
            float hn = sigf(go)*tanhf(cn);
            cbuf[off] = cn;
            cstore(hnext + off, hn);
        }
        ++bk; gbar(slots, bk, grp);
        { float* tp = hprev; hprev = hnext; hnext = tp; }  // hprev = new hd

        // ---- fused q + attention + log_softmax + argmax + feedback ----
        const int b = blk;                     // block = batch
        if (tid < 128)
            *(f4v*)(hds + (tid << 2)) = vload4(hprev + (size_t)b*Hn + (tid << 2));
        __syncthreads();
        // q[n] = b2[n] + sum_k hd[k]*W2[n,k]; 8-lane k-split, 4 chunks of 128 n
        {
            const int nl = tid >> 3;           // 0..127
            const int k8 = tid & 7;            // 0..7
            const float* hdp = hds + (k8 << 6);
            #pragma unroll
            for (int c = 0; c < 4; ++c) {
                const int n = (c << 7) + nl;
                const float* wr2 = W2 + (size_t)n*Hn + (k8 << 6);
                float acc = 0.f;
                for (int i = 0; i < 64; i += 4) {
                    float4 wv = *(const float4*)(wr2 + i);
                    acc += hdp[i]*wv.x + hdp[i+1]*wv.y
                         + hdp[i+2]*wv.z + hdp[i+3]*wv.w;
                }
                acc += __shfl_xor(acc, 1);
                acc += __shfl_xor(acc, 2);
                acc += __shfl_xor(acc, 4);
                if (k8 == 0) qsf[n] = acc + b2[n];
            }
        }
        __syncthreads();
        const int wv2 = tid >> 6;
        float qreg[8];
        #pragma unroll
        for (int j = 0; j < 8; ++j) qreg[j] = qsf[kb+j];
        const float* wbase = w1enc + ((size_t)b*Sn + (wv2 << 3))*Hn + kb;
        f4v w0 = *(const f4v*)wbase;
        f4v w1v = *(const f4v*)(wbase + 4);
        #pragma unroll
        for (int si = 0; si < 8; ++si) {
            f4v n0 = w0, n1 = w1v;             // 1-deep prefetch of next row
            if (si < 7) {
                const float* wr = wbase + (size_t)(si+1)*Hn;
                n0 = *(const f4v*)wr;
                n1 = *(const f4v*)(wr + 4);
            }
            float a = 0.f;
            a += vreg[0]*ftanh(w0[0] + qreg[0]);
            a += vreg[1]*ftanh(w0[1] + qreg[1]);
            a += vreg[2]*ftanh(w0[2] + qreg[2]);
            a += vreg[3]*ftanh(w0[3] + qreg[3]);
            a += vreg[4]*ftanh(w1v[0] + qreg[4]);
            a += vreg[5]*ftanh(w1v[1] + qreg[5]);
            a += vreg[6]*ftanh(w1v[2] + qreg[6]);
            a += vreg[7]*ftanh(w1v[3] + qreg[7]);
            a += __shfl_xor(a, 1);  a += __shfl_xor(a, 2);  a += __shfl_xor(a, 4);
            a += __shfl_xor(a, 8);  a += __shfl_xor(a, 16); a += __shfl_xor(a, 32);
            if (l64 == 0) us[(wv2 << 3) + si] = a;
            w0 = n0; w1v = n1;
        }
        __syncthreads();
        if (tid < 64) {
            float av = us[tid], c2 = us[tid+64];
            float mv; int mi;
            if (c2 > av) { mv = c2; mi = tid+64; } else { mv = av; mi = tid; }
            #pragma unroll
            for (int off2 = 1; off2 < 64; off2 <<= 1) {
                float ov = __shfl_xor(mv, off2);
                int   oi = __shfl_xor(mi, off2);
                if (ov > mv || (ov == mv && oi < mi)) { mv = ov; mi = oi; }
            }
            float es = expf(av - mv) + expf(c2 - mv);
            #pragma unroll
            for (int off2 = 1; off2 < 64; off2 <<= 1) es += __shfl_xor(es, off2);
            if (tid == 0) {
                rr[0] = mv; rr[1] = logf(es);
                out_ptr[b*Sn + t] = (float)mi;
                cstore(x_in + b, xseq[b*Sn + mi]);  // next decoder input
            }
        }
        __syncthreads();
        if (tid < Sn)
            out_scores[((size_t)b*Sn + t)*Sn + tid] = us[tid] - rr[0] - rr[1];
        if (t < Sn-1) { ++bk; gbar(slots, bk, grp); }
    }
#undef STAGE_H
}

extern "C" void kernel_launch(void* const* d_in, const int* in_sizes, int n_in,
                              void* d_out, int out_size, void* d_ws, size_t ws_size,
                              hipStream_t stream)
{
    const float* input_seq = (const float*)d_in[0];
    const float* We_e = (const float*)d_in[1],  *be_e = (const float*)d_in[2];
    const float* Wih_e = (const float*)d_in[3], *Whh_e = (const float*)d_in[4];
    const float* b_e = (const float*)d_in[5];
    const float* We_d = (const float*)d_in[6],  *be_d = (const float*)d_in[7];
    const float* Wih_d = (const float*)d_in[8], *Whh_d = (const float*)d_in[9];
    const float* b_d = (const float*)d_in[10];
    const float* W1 = (const float*)d_in[11], *b1 = (const float*)d_in[12];
    const float* W2 = (const float*)d_in[13], *b2 = (const float*)d_in[14];
    const float* v  = (const float*)d_in[15];  // bv cancels in log_softmax

    float* ws = (float*)d_ws;
    size_t o = 0;
    float* hb0  = ws + o; o += Bn*Hn;
    float* hb1  = ws + o; o += Bn*Hn;
    float* cbuf = ws + o; o += Bn*Hn;
    float* p1   = ws + o; o += G4;
    float* p0   = ws + o; o += G4;
    float* r1   = ws + o; o += G4;
    float* r0   = ws + o; o += G4;
    float* x_in = ws + o; o += 256;
    unsigned* barb = (unsigned*)(ws + o); o += 2048;   // slots + sys counters
    float* w1enc = ws + o;                             // 16.8M f32 = 64 MB

    hipMemsetAsync(hb0,  0, Bn*Hn*sizeof(float), stream);
    hipMemsetAsync(cbuf, 0, Bn*Hn*sizeof(float), stream);
    hipMemsetAsync(x_in, 0, (256+2048)*sizeof(float), stream); // x_in + barrier

    precompute_kernel<<<dim3(16), 256, 0, stream>>>(Wih_e, We_e, be_e, b_e,
                                                    Wih_d, We_d, be_d, b_d,
                                                    p1, p0, r1, r0);

    ptrnet_kernel<<<dim3(NBLK), dim3(NTHR), 0, stream>>>(
        input_seq, Whh_e, Whh_d, W1, b1, W2, b2, v,
        p1, p0, r1, r0, hb0, hb1, cbuf, x_in, w1enc, barb,
        (float*)d_out, (float*)d_out + (size_t)Bn*Sn*Sn);
}

// Round 16
// 12775.018 us; speedup vs baseline: 1.2091x; 1.2091x over previous
//
#include <hip/hip_runtime.h>
#include <hip/hip_fp16.h>

#define Bn 256
#define Sn 128
#define Hn 512
#define G4 2048
#define NBLK 256
#define NTHR 1024
#define HSTR 516   // padded LDS stride (floats)
#define LOG2E 1.4426950408889634f

typedef float f4v __attribute__((ext_vector_type(4)));

// ---- LSTM gates: ocml-based (bit-identical recurrence to rounds 10/12/13/14) ----
__device__ __forceinline__ float sigf(float x){
    float e = expf(-fabsf(x));
    float d = 1.f + e;
    return x >= 0.f ? 1.f/d : e/d;
}
// ---- attention-only fast tanh (validated r12/r13/r14: absmax 0.03125) ----
__device__ __forceinline__ float ftanh(float x){
    float e = __builtin_amdgcn_exp2f(-2.f * LOG2E * fabsf(x));
    float t = (1.f - e) * __builtin_amdgcn_rcpf(1.f + e);
    return copysignf(t, x);
}

// Agent-scope coherent access (coherence point, no L2 inv/wb).
__device__ __forceinline__ float cload(const float* p){
    return __hip_atomic_load((float*)p, __ATOMIC_RELAXED, __HIP_MEMORY_SCOPE_AGENT);
}
__device__ __forceinline__ void cstore(float* p, float v){
    __hip_atomic_store(p, v, __ATOMIC_RELAXED, __HIP_MEMORY_SCOPE_AGENT);
}
// Wide coherence-point load: volatile lowers to global_load_dwordx4 sc0 sc1
// (empirically coherent across XCDs: rounds 10/12/13/14 h-exchange correctness).
__device__ __forceinline__ f4v vload4(const float* p){
    return *(volatile const f4v*)p;
}

// ---- slot-store group barrier (16 blocks): no atomic RMW on the hot path ----
__device__ __forceinline__ void gbar(unsigned* slots, unsigned k, int grp){
    __syncthreads();
    if (threadIdx.x < 64) {
        if (threadIdx.x == 0)
            __hip_atomic_store(slots + grp, k, __ATOMIC_RELAXED, __HIP_MEMORY_SCOPE_AGENT);
        unsigned v = (threadIdx.x < 16)
            ? __hip_atomic_load(slots + threadIdx.x, __ATOMIC_RELAXED, __HIP_MEMORY_SCOPE_AGENT)
            : k;
        while (__ballot(v < k)) {
            __builtin_amdgcn_s_sleep(1);
            v = (threadIdx.x < 16)
                ? __hip_atomic_load(slots + threadIdx.x, __ATOMIC_RELAXED, __HIP_MEMORY_SCOPE_AGENT)
                : k;
        }
        asm volatile("" ::: "memory");
    }
    __syncthreads();
}
// One-shot transition barrier: release (wbl2) + acquire (inv) for w1enc handoff.
__device__ __forceinline__ void gbar_sys(unsigned* cnt){
    __syncthreads();
    if (threadIdx.x == 0) {
        __hip_atomic_fetch_add(cnt, 1u, __ATOMIC_RELEASE, __HIP_MEMORY_SCOPE_AGENT);
        while (__hip_atomic_load(cnt, __ATOMIC_RELAXED, __HIP_MEMORY_SCOPE_AGENT) < 16u)
            __builtin_amdgcn_s_sleep(1);
        (void)__hip_atomic_load(cnt, __ATOMIC_ACQUIRE, __HIP_MEMORY_SCOPE_AGENT);
    }
    __syncthreads();
}

// ---- rank-1 collapse of the input-side GEMMs (F_IN == 1) ----
__global__ void precompute_kernel(
    const float* __restrict__ Wih_e, const float* __restrict__ We_e,
    const float* __restrict__ be_e,  const float* __restrict__ b_e,
    const float* __restrict__ Wih_d, const float* __restrict__ We_d,
    const float* __restrict__ be_d,  const float* __restrict__ b_d,
    float* __restrict__ p1, float* __restrict__ p0,
    float* __restrict__ r1, float* __restrict__ r0)
{
    int j = blockIdx.x*blockDim.x + threadIdx.x;   // 0..4095
    bool dec = j >= G4;
    int jj = dec ? j - G4 : j;
    const float* Wih = dec ? Wih_d : Wih_e;
    const float* We  = dec ? We_d  : We_e;
    const float* be  = dec ? be_d  : be_e;
    const float* bb  = dec ? b_d   : b_e;
    float s1 = 0.f, s0 = 0.f;
    for (int k = 0; k < Hn; ++k) {
        float w = Wih[jj*Hn + k];
        s1 += w * We[k];
        s0 += w * be[k];
    }
    s0 += bb[jj];
    if (dec) { r1[jj] = s1; r0[jj] = s0; }
    else     { p1[jj] = s1; p0[jj] = s0; }
}

// ---- whole pointer network, one persistent kernel (r14 structure,
//      + 1-deep w1enc row prefetch in attention) ----
__global__ __launch_bounds__(NTHR, 4) void ptrnet_kernel(
    const float* __restrict__ xseq,
    const float* __restrict__ Whh_e, const float* __restrict__ Whh_d,
    const float* __restrict__ W1, const float* __restrict__ b1,
    const float* __restrict__ W2, const float* __restrict__ b2,
    const float* __restrict__ vv,
    const float* __restrict__ p1, const float* __restrict__ p0,
    const float* __restrict__ r1, const float* __restrict__ r0,
    float* __restrict__ hb0, float* __restrict__ hb1,
    float* __restrict__ cbuf, float* __restrict__ qbuf,
    float* __restrict__ x_in, float* __restrict__ w1enc,
    unsigned* __restrict__ barb,
    float* __restrict__ out_scores, float* __restrict__ out_ptr)
{
    __shared__ float smem[16*HSTR + 512*5 + 16];   // 43.3 KB
    float* hs  = smem;                 // [16][HSTR] h-tile
    float* red = smem + 16*HSTR;       // split-k partials
    float* qs  = smem;                 // attn aliases (phases disjoint)
    float* us  = smem + Hn;            // 128 logits
    float* rr  = smem + Hn + Sn + 8;   // {max, log-sum-exp}

    const int blk = blockIdx.x;
    const int tid = threadIdx.x;
    const int bt  = blk >> 4, grp = blk & 15;
    const int b0  = bt << 4;
    const int tb  = tid & 15;
    const int hh  = (tid >> 4) & 31;
    const int ks  = tid >> 9;
    const int hg  = (grp << 5) + hh;
    const int kofs = ks << 8;
    unsigned* slots  = barb + bt*64;           // 16 slots in one 64B line
    unsigned* syscnt = barb + 1024 + bt*64;    // one-shot transition counter
    unsigned bk = 0;
    float* hprev = hb0;
    float* hnext = hb1;

    // v is loop-invariant: hoist per-lane slice into registers
    const int l64 = tid & 63;
    const int kb = l64 << 3;
    float vreg[8];
    #pragma unroll
    for (int j = 0; j < 8; ++j) vreg[j] = vv[kb+j];

// 16 rows x 512 floats = 2048 f4v over 1024 threads: 2 coherent 16B loads each.
#define STAGE_H(SRC) do { \
    for (int i_ = tid; i_ < 16*128; i_ += NTHR) { \
        int r_ = i_ >> 7; int c4_ = (i_ & 127) << 2; \
        *(f4v*)(hs + r_*HSTR + c4_) = vload4((SRC) + (size_t)(b0+r_)*Hn + c4_); \
    } __syncthreads(); } while(0)

    // ================= encoder: t = 0..128 (t==128 emits only w1enc[127]) ===
    for (int t = 0; t <= Sn; ++t) {
        STAGE_H(hprev);
        float a0=0.f,a1=0.f,a2=0.f,a3=0.f,a4=0.f;
        {
            const float* hrow = hs + tb*HSTR + kofs;
            const float* w0 = Whh_e + (size_t)hg*Hn          + kofs;
            const float* w1r= Whh_e + (size_t)(Hn+hg)*Hn     + kofs;
            const float* w2r= Whh_e + (size_t)(2*Hn+hg)*Hn   + kofs;
            const float* w3r= Whh_e + (size_t)(3*Hn+hg)*Hn   + kofs;
            const float* w4r= W1    + (size_t)hg*Hn          + kofs;
            for (int i = 0; i < 256; i += 4) {
                float4 hv = *(const float4*)(hrow + i);
                float4 x0 = *(const float4*)(w0 + i);
                float4 x1 = *(const float4*)(w1r + i);
                float4 x2 = *(const float4*)(w2r + i);
                float4 x3 = *(const float4*)(w3r + i);
                float4 x4 = *(const float4*)(w4r + i);
                a0 += hv.x*x0.x + hv.y*x0.y + hv.z*x0.z + hv.w*x0.w;
                a1 += hv.x*x1.x + hv.y*x1.y + hv.z*x1.z + hv.w*x1.w;
                a2 += hv.x*x2.x + hv.y*x2.y + hv.z*x2.z + hv.w*x2.w;
                a3 += hv.x*x3.x + hv.y*x3.y + hv.z*x3.z + hv.w*x3.w;
                a4 += hv.x*x4.x + hv.y*x4.y + hv.z*x4.z + hv.w*x4.w;
            }
        }
        if (ks) {
            float* rp = red + (size_t)(tid - 512)*5;
            rp[0]=a0; rp[1]=a1; rp[2]=a2; rp[3]=a3; rp[4]=a4;
        }
        __syncthreads();
        if (!ks) {
            const float* rp = red + (size_t)tid*5;
            a0+=rp[0]; a1+=rp[1]; a2+=rp[2]; a3+=rp[3]; a4+=rp[4];
            size_t off = (size_t)(b0+tb)*Hn + hg;
            if (t < Sn) {
                float xv = xseq[(b0+tb)*Sn + t];
                float gi = a0 + xv*p1[hg]      + p0[hg];
                float gf = a1 + xv*p1[Hn+hg]   + p0[Hn+hg];
                float gg = a2 + xv*p1[2*Hn+hg] + p0[2*Hn+hg];
                float go = a3 + xv*p1[3*Hn+hg] + p0[3*Hn+hg];
                float cn = sigf(gf)*cbuf[off] + sigf(gi)*tanhf(gg);
                float hn = sigf(go)*tanhf(cn);
                cbuf[off] = cn;
                cstore(hnext + off, hn);
            }
            if (t > 0)
                w1enc[((size_t)(b0+tb)*Sn + (t-1))*Hn + hg] = a4 + b1[hg];
        }
        if (t == Sn) gbar_sys(syscnt);     // w1enc handoff: wbl2 + inv (once)
        else         { ++bk; gbar(slots, bk, grp); }
        if (t < Sn) { float* tp = hprev; hprev = hnext; hnext = tp; }
    }

    // ================= decoder: 128 steps of LSTM -> q -> attention =========
    for (int t = 0; t < Sn; ++t) {
        // ---- dec LSTM ----
        STAGE_H(hprev);
        float a0=0.f,a1=0.f,a2=0.f,a3=0.f;
        {
            const float* hrow = hs + tb*HSTR + kofs;
            const float* w0 = Whh_d + (size_t)hg*Hn        + kofs;
            const float* w1r= Whh_d + (size_t)(Hn+hg)*Hn   + kofs;
            const float* w2r= Whh_d + (size_t)(2*Hn+hg)*Hn + kofs;
            const float* w3r= Whh_d + (size_t)(3*Hn+hg)*Hn + kofs;
            for (int i = 0; i < 256; i += 4) {
                float4 hv = *(const float4*)(hrow + i);
                float4 x0 = *(const float4*)(w0 + i);
                float4 x1 = *(const float4*)(w1r + i);
                float4 x2 = *(const float4*)(w2r + i);
                float4 x3 = *(const float4*)(w3r + i);
                a0 += hv.x*x0.x + hv.y*x0.y + hv.z*x0.z + hv.w*x0.w;
                a1 += hv.x*x1.x + hv.y*x1.y + hv.z*x1.z + hv.w*x1.w;
                a2 += hv.x*x2.x + hv.y*x2.y + hv.z*x2.z + hv.w*x2.w;
                a3 += hv.x*x3.x + hv.y*x3.y + hv.z*x3.z + hv.w*x3.w;
            }
        }
        if (ks) {
            float* rp = red + (size_t)(tid - 512)*4;
            rp[0]=a0; rp[1]=a1; rp[2]=a2; rp[3]=a3;
        }
        __syncthreads();
        if (!ks) {
            const float* rp = red + (size_t)tid*4;
            a0+=rp[0]; a1+=rp[1]; a2+=rp[2]; a3+=rp[3];
            size_t off = (size_t)(b0+tb)*Hn + hg;
            float xv = cload(x_in + b0 + tb);
            float gi = a0 + xv*r1[hg]      + r0[hg];
            float gf = a1 + xv*r1[Hn+hg]   + r0[Hn+hg];
            float gg = a2 + xv*r1[2*Hn+hg] + r0[2*Hn+hg];
            float go = a3 + xv*r1[3*Hn+hg] + r0[3*Hn+hg];
            float cn = sigf(gf)*cbuf[off] + sigf(gi)*tanhf(gg);
            float hn = sigf(go)*tanhf(cn);
            cbuf[off] = cn;
            cstore(hnext + off, hn);
        }
        ++bk; gbar(slots, bk, grp);
        { float* tp = hprev; hprev = hnext; hnext = tp; }  // hprev = new hd

        // ---- q = hd @ W2^T + b2 ----
        STAGE_H(hprev);
        float qa = 0.f;
        {
            const float* hrow = hs + tb*HSTR + kofs;
            const float* wq = W2 + (size_t)hg*Hn + kofs;
            for (int i = 0; i < 256; i += 4) {
                float4 hv = *(const float4*)(hrow + i);
                float4 wv = *(const float4*)(wq + i);
                qa += hv.x*wv.x + hv.y*wv.y + hv.z*wv.z + hv.w*wv.w;
            }
        }
        if (ks) red[tid - 512] = qa;
        __syncthreads();
        if (!ks) cstore(qbuf + (size_t)(b0+tb)*Hn + hg, qa + red[tid] + b2[hg]);
        ++bk; gbar(slots, bk, grp);

        // ---- attention + log_softmax + argmax + feedback (block = batch) ----
        const int b = blk;
        if (tid < 128) {   // 512 floats of q via 128 wide coherent loads
            f4v q4 = vload4(qbuf + (size_t)b*Hn + (tid << 2));
            *(f4v*)(qs + (tid << 2)) = q4;
        }
        __syncthreads();
        const int wv2 = tid >> 6;
        float qreg[8];
        #pragma unroll
        for (int j = 0; j < 8; ++j) qreg[j] = qs[kb+j];
        const float* wbase = w1enc + ((size_t)b*Sn + (wv2 << 3))*Hn + kb;
        f4v w0 = *(const f4v*)wbase;
        f4v w1v = *(const f4v*)(wbase + 4);
        #pragma unroll
        for (int si = 0; si < 8; ++si) {
            f4v n0 = w0, n1 = w1v;             // 1-deep prefetch of next row
            if (si < 7) {
                const float* wr = wbase + (size_t)(si+1)*Hn;
                n0 = *(const f4v*)wr;
                n1 = *(const f4v*)(wr + 4);
            }
            float a = 0.f;
            a += vreg[0]*ftanh(w0[0] + qreg[0]);
            a += vreg[1]*ftanh(w0[1] + qreg[1]);
            a += vreg[2]*ftanh(w0[2] + qreg[2]);
            a += vreg[3]*ftanh(w0[3] + qreg[3]);
            a += vreg[4]*ftanh(w1v[0] + qreg[4]);
            a += vreg[5]*ftanh(w1v[1] + qreg[5]);
            a += vreg[6]*ftanh(w1v[2] + qreg[6]);
            a += vreg[7]*ftanh(w1v[3] + qreg[7]);
            a += __shfl_xor(a, 1);  a += __shfl_xor(a, 2);  a += __shfl_xor(a, 4);
            a += __shfl_xor(a, 8);  a += __shfl_xor(a, 16); a += __shfl_xor(a, 32);
            if (l64 == 0) us[(wv2 << 3) + si] = a;
            w0 = n0; w1v = n1;
        }
        __syncthreads();
        if (tid < 64) {
            float av = us[tid], c2 = us[tid+64];
            float mv; int mi;
            if (c2 > av) { mv = c2; mi = tid+64; } else { mv = av; mi = tid; }
            #pragma unroll
            for (int off2 = 1; off2 < 64; off2 <<= 1) {
                float ov = __shfl_xor(mv, off2);
                int   oi = __shfl_xor(mi, off2);
                if (ov > mv || (ov == mv && oi < mi)) { mv = ov; mi = oi; }
            }
            float es = expf(av - mv) + expf(c2 - mv);
            #pragma unroll
            for (int off2 = 1; off2 < 64; off2 <<= 1) es += __shfl_xor(es, off2);
            if (tid == 0) {
                rr[0] = mv; rr[1] = logf(es);
                out_ptr[b*Sn + t] = (float)mi;
                cstore(x_in + b, xseq[b*Sn + mi]);  // next decoder input
            }
        }
        __syncthreads();
        if (tid < Sn)
            out_scores[((size_t)b*Sn + t)*Sn + tid] = us[tid] - rr[0] - rr[1];
        if (t < Sn-1) { ++bk; gbar(slots, bk, grp); }
    }
#undef STAGE_H
}

extern "C" void kernel_launch(void* const* d_in, const int* in_sizes, int n_in,
                              void* d_out, int out_size, void* d_ws, size_t ws_size,
                              hipStream_t stream)
{
    const float* input_seq = (const float*)d_in[0];
    const float* We_e = (const float*)d_in[1],  *be_e = (const float*)d_in[2];
    const float* Wih_e = (const float*)d_in[3], *Whh_e = (const float*)d_in[4];
    const float* b_e = (const float*)d_in[5];
    const float* We_d = (const float*)d_in[6],  *be_d = (const float*)d_in[7];
    const float* Wih_d = (const float*)d_in[8], *Whh_d = (const float*)d_in[9];
    const float* b_d = (const float*)d_in[10];
    const float* W1 = (const float*)d_in[11], *b1 = (const float*)d_in[12];
    const float* W2 = (const float*)d_in[13], *b2 = (const float*)d_in[14];
    const float* v  = (const float*)d_in[15];  // bv cancels in log_softmax

    float* ws = (float*)d_ws;
    size_t o = 0;
    float* hb0  = ws + o; o += Bn*Hn;
    float* hb1  = ws + o; o += Bn*Hn;
    float* cbuf = ws + o; o += Bn*Hn;
    float* qbuf = ws + o; o += Bn*Hn;
    float* p1   = ws + o; o += G4;
    float* p0   = ws + o; o += G4;
    float* r1   = ws + o; o += G4;
    float* r0   = ws + o; o += G4;
    float* x_in = ws + o; o += 256;
    unsigned* barb = (unsigned*)(ws + o); o += 2048;   // slots + sys counters
    float* w1enc = ws + o;                             // 16.8M f32 = 64 MB

    hipMemsetAsync(hb0,  0, Bn*Hn*sizeof(float), stream);
    hipMemsetAsync(cbuf, 0, Bn*Hn*sizeof(float), stream);
    hipMemsetAsync(x_in, 0, (256+2048)*sizeof(float), stream); // x_in + barrier

    precompute_kernel<<<dim3(16), 256, 0, stream>>>(Wih_e, We_e, be_e, b_e,
                                                    Wih_d, We_d, be_d, b_d,
                                                    p1, p0, r1, r0);

    ptrnet_kernel<<<dim3(NBLK), dim3(NTHR), 0, stream>>>(
        input_seq, Whh_e, Whh_d, W1, b1, W2, b2, v,
        p1, p0, r1, r0, hb0, hb1, cbuf, qbuf, x_in, w1enc, barb,
        (float*)d_out, (float*)d_out + (size_t)Bn*Sn*Sn);
}